// Round 5
// baseline (207.166 us; speedup 1.0000x reference)
//
#include <hip/hip_runtime.h>

#define HH 512
#define WW 512
#define HO 502
#define WO 502
#define KS 11
#define OTH 16                 // v-rows per tile
#define RPT 4                  // v-rows per thread in phase 1 (4 groups)
#define NR  (RPT + KS - 1)     // 14 input rows per thread
#define OTW 52                 // output tile cols
#define VW  62                 // v-buffer cols = OTW + KS - 1
#define RS  18                 // row stride (dwords), EVEN -> b64 LDS ops
#define CHS (VW * RS)          // 1116 dwords per channel
#define CPT 4                  // output cols per thread in phase 2
#define NPOS (CPT + KS - 1)    // 14 tap positions
#define NCG 13                 // active col-groups (13*4 = 52 = OTW)

typedef float f32x2 __attribute__((ext_vector_type(2)));

// symmetric gaussian lookup, k compile-time
#define GW(k) g[(k) < 6 ? (k) : 10 - (k)]

__global__ __launch_bounds__(256) void ssim_sep_kernel(
    const float* __restrict__ img1, const float* __restrict__ img2,
    const float* __restrict__ win, double* __restrict__ acc)
{
    __shared__ __align__(16) float vbuf[5 * CHS];   // 22,320 B -> 7 blocks/CU
    __shared__ float wsum[4];

    const int tid = threadIdx.x;
    const int tile_c0 = blockIdx.x * OTW;
    const int tile_r0 = blockIdx.y * OTH;
    const size_t base = (size_t)blockIdx.z * (HH * WW);

    // 1-D gaussian from separable 2-D window: g[k] = w[5][k]/sqrt(w[5][5]); symmetric
    float g[6];
    {
        double inv = 1.0 / sqrt((double)win[5 * KS + 5]);
        #pragma unroll
        for (int k = 0; k < 6; ++k)
            g[k] = (float)((double)win[5 * KS + k] * inv);
    }

    // ---------- phase 1: vertical conv, global -> regs -> LDS (transposed, paired) ----------
    {
        const int lane = tid & 63;          // v column
        const int j0 = (tid >> 6) * RPT;    // first v-row owned (0,4,8,12)
        int gc = tile_c0 + lane;
        if (gc > WW - 1) gc = WW - 1;       // clamped cols feed only discarded outputs

        const float* p1 = img1 + base;
        const float* p2 = img2 + base;

        float a[NR], b[NR];
        #pragma unroll
        for (int ri = 0; ri < NR; ++ri) {
            int gr = tile_r0 + j0 + ri;
            if (gr > HH - 1) gr = HH - 1;   // clamped rows feed only discarded outputs
            const size_t ro = (size_t)gr * WW;
            a[ri] = p1[ro + gc];
            b[ri] = p2[ro + gc];
        }

        float accv[5][RPT];
        #pragma unroll
        for (int ch = 0; ch < 5; ++ch)
            #pragma unroll
            for (int j = 0; j < RPT; ++j) accv[ch][j] = 0.f;

        #pragma unroll
        for (int ri = 0; ri < NR; ++ri) {
            float av = a[ri], bv = b[ri];
            float aa = av * av, bb = bv * bv, ab = av * bv;
            #pragma unroll
            for (int j = 0; j < RPT; ++j) {
                int k = ri - j;
                if (k >= 0 && k < KS) {     // folds at compile time
                    float w = GW(k);
                    accv[0][j] += w * av;
                    accv[1][j] += w * bv;
                    accv[2][j] += w * aa;
                    accv[3][j] += w * bb;
                    accv[4][j] += w * ab;
                }
            }
        }
        if (lane < VW) {
            const int cb = lane * RS + j0;  // even -> 8B aligned
            #pragma unroll
            for (int ch = 0; ch < 5; ++ch)
                #pragma unroll
                for (int m = 0; m < RPT / 2; ++m) {
                    f32x2 w2 = {accv[ch][2 * m], accv[ch][2 * m + 1]};
                    *reinterpret_cast<f32x2*>(&vbuf[ch * CHS + cb + 2 * m]) = w2;
                }
        }
    }
    __syncthreads();

    // ---------- phase 2: horizontal conv + SSIM (row-pairs via b64 reads) ----------
    float lsum = 0.f;
    {
        const int rp = tid & 7;             // row-pair: rows 2rp, 2rp+1
        const int cg = tid >> 3;            // col group
        if (cg < NCG) {
            const int c0 = cg * CPT;
            const int rbase = 2 * rp;

            float acc2[5][2][CPT];
            #pragma unroll
            for (int ch = 0; ch < 5; ++ch)
                #pragma unroll
                for (int rr = 0; rr < 2; ++rr)
                    #pragma unroll
                    for (int j = 0; j < CPT; ++j) acc2[ch][rr][j] = 0.f;

            #pragma unroll
            for (int ch = 0; ch < 5; ++ch) {
                const float* vp = &vbuf[ch * CHS + rbase];
                #pragma unroll
                for (int i = 0; i < NPOS; ++i) {
                    int ci = c0 + i;                       // <= 61, in-bounds
                    f32x2 v = *reinterpret_cast<const f32x2*>(&vp[ci * RS]);
                    #pragma unroll
                    for (int j = 0; j < CPT; ++j) {
                        int k = i - j;
                        if (k >= 0 && k < KS) {            // folds at compile time
                            float w = GW(k);
                            acc2[ch][0][j] += w * v.x;
                            acc2[ch][1][j] += w * v.y;
                        }
                    }
                }
            }

            const float c1 = 1e-4f, c2 = 9e-4f;            // L = 1 for [0,1) inputs
            #pragma unroll
            for (int rr = 0; rr < 2; ++rr) {
                const int orow = tile_r0 + rbase + rr;
                #pragma unroll
                for (int j = 0; j < CPT; ++j) {
                    int ocol = tile_c0 + c0 + j;
                    if (orow < HO && ocol < WO) {
                        float mu1 = acc2[0][rr][j], mu2 = acc2[1][rr][j];
                        float e11 = acc2[2][rr][j], e22 = acc2[3][rr][j], e12 = acc2[4][rr][j];
                        float mu1s = mu1 * mu1, mu2s = mu2 * mu2, mu12 = mu1 * mu2;
                        float sg1 = e11 - mu1s, sg2 = e22 - mu2s, sg12 = e12 - mu12;
                        float num = (2.f * mu12 + c1) * (2.f * sg12 + c2);
                        float den = (mu1s + mu2s + c1) * (sg1 + sg2 + c2);
                        lsum += num * __builtin_amdgcn_rcpf(den);
                    }
                }
            }
        }
    }

    // ---------- reduction ----------
    #pragma unroll
    for (int off = 32; off; off >>= 1)
        lsum += __shfl_down(lsum, off, 64);
    if ((tid & 63) == 0) wsum[tid >> 6] = lsum;
    __syncthreads();
    if (tid == 0) {
        double t = (double)wsum[0] + (double)wsum[1] +
                   (double)wsum[2] + (double)wsum[3];
        atomicAdd(acc, t);
    }
}

__global__ void ssim_finalize(const double* __restrict__ acc,
                              float* __restrict__ out)
{
    out[0] = (float)(acc[0] / (double)(16LL * 3LL * (long long)HO * (long long)WO));
}

extern "C" void kernel_launch(void* const* d_in, const int* in_sizes, int n_in,
                              void* d_out, int out_size, void* d_ws, size_t ws_size,
                              hipStream_t stream) {
    const float* img1 = (const float*)d_in[0];
    const float* img2 = (const float*)d_in[1];
    const float* win  = (const float*)d_in[2];  // (3,1,11,11); channels identical
    float* out = (float*)d_out;
    double* acc = (double*)d_ws;

    hipMemsetAsync(acc, 0, sizeof(double), stream);

    dim3 grid((WO + OTW - 1) / OTW, (HO + OTH - 1) / OTH, 16 * 3);
    ssim_sep_kernel<<<grid, 256, 0, stream>>>(img1, img2, win, acc);
    ssim_finalize<<<1, 1, 0, stream>>>(acc, out);
}